// Round 18
// baseline (389.020 us; speedup 1.0000x reference)
//
#include <hip/hip_runtime.h>

#define CDIM  3072
#define MROWS 8192
#define NOUT  9216
#define NW    24     // K windows of 128 bytes (2 x K=64 MFMA slabs)

typedef __bf16 bf16x8 __attribute__((ext_vector_type(8)));
typedef float f32x4 __attribute__((ext_vector_type(4)));
typedef int i32x4 __attribute__((ext_vector_type(4)));

__device__ __forceinline__ unsigned short f2bf(float f) {
  union { float f; unsigned int u; } v; v.f = f;
  unsigned int u = v.u;
  return (unsigned short)((u + 0x7fffu + ((u >> 16) & 1u)) >> 16);  // RNE
}
__device__ __forceinline__ float bfu_lo(unsigned int u) {
  union { unsigned int v; float f; } x; x.v = u << 16; return x.f;
}
__device__ __forceinline__ float bfu_hi(unsigned int u) {
  union { unsigned int v; float f; } x; x.v = u & 0xffff0000u; return x.f;
}
__device__ __forceinline__ void gld16(const void* g, void* l) {
  __builtin_amdgcn_global_load_lds(
      (const __attribute__((address_space(1))) void*)g,
      (__attribute__((address_space(3))) void*)l, 16, 0, 0);
}

#define BARRIER() asm volatile("s_barrier" ::: "memory")
#define LGKM0()   asm volatile("s_waitcnt lgkmcnt(0)" ::: "memory")

template<int N> __device__ __forceinline__ void vmw() {
  if constexpr (N == 0) asm volatile("s_waitcnt vmcnt(0)" ::: "memory");
}

// Requant helper: q packed int8x4 (exact reference int4 levels), f = 16*s/S.
__device__ __forceinline__ unsigned int requant4(unsigned int u, float f) {
  const int q0 = (int)(signed char)(u & 0xff);
  const int q1 = (int)(signed char)((u >> 8) & 0xff);
  const int q2 = (int)(signed char)((u >> 16) & 0xff);
  const int q3 = (int)(signed char)(u >> 24);
  const int r0 = (int)rintf((float)q0 * f);
  const int r1 = (int)rintf((float)q1 * f);
  const int r2 = (int)rintf((float)q2 * f);
  const int r3 = (int)rintf((float)q3 * f);
  return (r0 & 0xff) | ((r1 & 0xff) << 8) | ((r2 & 0xff) << 16)
       | ((unsigned int)(r3 & 0xff) << 24);
}

// ---------------- K1: fused prep (unchanged from r14).
__global__ __launch_bounds__(256) void k_prep(
    const float* __restrict__ wt, const float* __restrict__ pu,
    const float* __restrict__ x, const float* __restrict__ smooth,
    const float* __restrict__ pd,
    signed char* __restrict__ Bq, float* __restrict__ Sb_r,
    unsigned short* __restrict__ Blor,
    signed char* __restrict__ Aq, float* __restrict__ Sa_r,
    unsigned short* __restrict__ Alor) {
  __shared__ unsigned short xsb[4][3072];
  __shared__ float plds[4][32][33];
  __shared__ float sred[4];
  const int tid = threadIdx.x;

  if (blockIdx.x < NOUT) {
    const int row = blockIdx.x;
    unsigned int u[3]; float sl[3];
    #pragma unroll
    for (int it = 0; it < 3; ++it) {
      const int c = it * 1024 + tid * 4;
      const float4 v = *(const float4*)&wt[(size_t)row * CDIM + c];
      float am = fmaxf(fmaxf(fabsf(v.x), fabsf(v.y)), fmaxf(fabsf(v.z), fabsf(v.w)));
      #pragma unroll
      for (int off = 1; off < 16; off <<= 1) am = fmaxf(am, __shfl_xor(am, off));
      const float s = fmaxf(am / 7.0f, 1e-8f);                 // IEEE div (ref-exact)
      union { signed char c[4]; unsigned int u; } pk;
      pk.c[0] = (signed char)(int)fminf(fmaxf(rintf(v.x / s), -8.f), 7.f);
      pk.c[1] = (signed char)(int)fminf(fmaxf(rintf(v.y / s), -8.f), 7.f);
      pk.c[2] = (signed char)(int)fminf(fmaxf(rintf(v.z / s), -8.f), 7.f);
      pk.c[3] = (signed char)(int)fminf(fmaxf(rintf(v.w / s), -8.f), 7.f);
      u[it] = pk.u; sl[it] = s;
    }
    float smax = fmaxf(fmaxf(sl[0], sl[1]), sl[2]);
    #pragma unroll
    for (int off = 16; off < 64; off <<= 1) smax = fmaxf(smax, __shfl_xor(smax, off));
    if ((tid & 63) == 0) sred[tid >> 6] = smax;
    __syncthreads();
    const float S = fmaxf(fmaxf(sred[0], sred[1]), fmaxf(sred[2], sred[3]));
    const float inv16 = 16.0f / S;
    #pragma unroll
    for (int it = 0; it < 3; ++it) {
      const int c = it * 1024 + tid * 4;
      *(unsigned int*)&Bq[(size_t)row * CDIM + c] = requant4(u[it], sl[it] * inv16);
    }
    if (tid == 0) Sb_r[row] = S * 0.0625f;   // S/16
    if (tid < 32) Blor[row * 32 + tid] = f2bf(pu[row * 32 + tid]);
    return;
  }

  const int blk = blockIdx.x - NOUT;
  const int w = tid >> 6, l = tid & 63;
  const int row = blk * 4 + w;
  const float* xr = x + (size_t)row * CDIM;
  unsigned int u[12]; float sl[12];

  #pragma unroll
  for (int it = 0; it < 12; ++it) {
    const int c = it * 256 + l * 4;
    const float4 xv = *(const float4*)&xr[c];
    const float4 sm = *(const float4*)&smooth[c];
    float4 xs;
    xs.x = xv.x / sm.x; xs.y = xv.y / sm.y;   // exact IEEE div
    xs.z = xv.z / sm.z; xs.w = xv.w / sm.w;
    ushort4 xb;
    xb.x = f2bf(xs.x); xb.y = f2bf(xs.y); xb.z = f2bf(xs.z); xb.w = f2bf(xs.w);
    *(ushort4*)&xsb[w][c] = xb;
    float am = fmaxf(fmaxf(fabsf(xs.x), fabsf(xs.y)), fmaxf(fabsf(xs.z), fabsf(xs.w)));
    #pragma unroll
    for (int off = 1; off < 16; off <<= 1) am = fmaxf(am, __shfl_xor(am, off));
    const float s = fmaxf(am / 7.0f, 1e-8f);
    union { signed char c[4]; unsigned int u; } pk;
    pk.c[0] = (signed char)(int)fminf(fmaxf(rintf(xs.x / s), -8.f), 7.f);
    pk.c[1] = (signed char)(int)fminf(fmaxf(rintf(xs.y / s), -8.f), 7.f);
    pk.c[2] = (signed char)(int)fminf(fmaxf(rintf(xs.z / s), -8.f), 7.f);
    pk.c[3] = (signed char)(int)fminf(fmaxf(rintf(xs.w / s), -8.f), 7.f);
    u[it] = pk.u; sl[it] = s;
  }
  float smax = sl[0];
  #pragma unroll
  for (int it = 1; it < 12; ++it) smax = fmaxf(smax, sl[it]);
  #pragma unroll
  for (int off = 16; off < 64; off <<= 1) smax = fmaxf(smax, __shfl_xor(smax, off));
  const float S = smax;
  const float inv16 = 16.0f / S;
  #pragma unroll
  for (int it = 0; it < 12; ++it) {
    const int c = it * 256 + l * 4;
    *(unsigned int*)&Aq[(size_t)row * CDIM + c] = requant4(u[it], sl[it] * inv16);
  }
  if (l == 0) Sa_r[row] = S * 0.0625f;     // S/16
  __syncthreads();

  const int ch = tid >> 3, rg = tid & 7;
  float acc[4][4] = {};
  for (int i = 0; i < 48; ++i) {
    const int c = ch * 2 + i * 64;
    const float4 p0 = *(const float4*)&pd[(size_t)c * 32 + rg * 4];
    const float4 p1 = *(const float4*)&pd[(size_t)(c + 1) * 32 + rg * 4];
    #pragma unroll
    for (int r4 = 0; r4 < 4; ++r4) {
      const unsigned int uu = *(const unsigned int*)&xsb[r4][c];
      const float xa = bfu_lo(uu), xb = bfu_hi(uu);
      acc[r4][0] += xa * p0.x + xb * p1.x;
      acc[r4][1] += xa * p0.y + xb * p1.y;
      acc[r4][2] += xa * p0.z + xb * p1.z;
      acc[r4][3] += xa * p0.w + xb * p1.w;
    }
  }
  #pragma unroll
  for (int r4 = 0; r4 < 4; ++r4)
    #pragma unroll
    for (int jj = 0; jj < 4; ++jj)
      plds[r4][rg * 4 + jj][ch] = acc[r4][jj];
  __syncthreads();
  if (tid < 128) {
    const int rr = tid >> 5, r = tid & 31;
    float ssum = 0.f;
    #pragma unroll
    for (int cc = 0; cc < 32; ++cc) ssum += plds[rr][r][cc];
    Alor[(size_t)(blk * 4 + rr) * 32 + r] = f2bf(ssum);
  }
}

// ---------------- K3: i8 256x256 GEMM, 2-phase windows (32-MFMA clusters).
// 512 thr, 8 waves (2M x 4N, 128x64/wave). Window = BK 128 bytes (2 K-slabs
// of 64). LDS regions 16 KB = [256 rows][64 B]: A0[p]=p*16K, A1[p]=32K+p*16K,
// B0[p]=64K+p*16K, B1[p]=96K+p*16K. Swizzle chunk ^= (row>>1)&3 (0-conflict).
// Window t (par=t&1):
//  phase A: read b kk0+kk1 (8) + a mi0-3 kk0+kk1 (8); stage ALL 8 loads of
//           window t+1 (or 4 lora loads at t=NW-1); BARRIER; LGKM0; 32 MFMA.
//  phase B: read a mi4-7 (8); BARRIER; LGKM0; 32 MFMA; vmcnt(0); BARRIER.
// WAR: stages target par^1 regions last read in window t-1 (fenced by its end
// barrier). RAW: vmcnt(0) retires all 8 with >=1-window distance (~2300cy).
__device__ __forceinline__ void gemm_window2(
    char* lds, i32x4 (&acc)[8][4],
    const signed char* Asrc, const signed char* Bsrc,
    const char* AlorP, const char* BlorP,
    int tid, int arow, int brow, int fsb, int par, int t, int mode) {
  // mode: 0 = stage window t+1; 1 = stage lora; 2 = no stage
  const int A0 = par * 16384;
  const int A1 = 32768 + par * 16384;
  const int B0 = 65536 + par * 16384;
  const int B1 = 98304 + par * 16384;
  const int A0n = (par ^ 1) * 16384;
  const int A1n = 32768 + (par ^ 1) * 16384;
  const int B0n = 65536 + (par ^ 1) * 16384;
  const int B1n = 98304 + (par ^ 1) * 16384;
  i32x4 a[8], b[8];

  // ---- phase A
  #pragma unroll
  for (int ni = 0; ni < 4; ++ni) {
    b[ni]     = *(const i32x4*)(lds + B0 + (brow + ni * 16) * 64 + fsb);
    b[4 + ni] = *(const i32x4*)(lds + B1 + (brow + ni * 16) * 64 + fsb);
  }
  #pragma unroll
  for (int mi = 0; mi < 4; ++mi) {
    a[mi]     = *(const i32x4*)(lds + A0 + (arow + mi * 16) * 64 + fsb);
    a[4 + mi] = *(const i32x4*)(lds + A1 + (arow + mi * 16) * 64 + fsb);
  }
  if (mode == 0) {
    const int kc = (t + 1) * 128;
    gld16(Asrc + kc,                            lds + A0n + tid * 16);
    gld16(Asrc + (size_t)128 * CDIM + kc,       lds + A0n + 8192 + tid * 16);
    gld16(Asrc + kc + 64,                       lds + A1n + tid * 16);
    gld16(Asrc + (size_t)128 * CDIM + kc + 64,  lds + A1n + 8192 + tid * 16);
    gld16(Bsrc + kc,                            lds + B0n + tid * 16);
    gld16(Bsrc + (size_t)128 * CDIM + kc,       lds + B0n + 8192 + tid * 16);
    gld16(Bsrc + kc + 64,                       lds + B1n + tid * 16);
    gld16(Bsrc + (size_t)128 * CDIM + kc + 64,  lds + B1n + 8192 + tid * 16);
  } else if (mode == 1) {
    gld16(AlorP,            lds + A0n + tid * 16);
    gld16(AlorP + 128 * 64, lds + A0n + 8192 + tid * 16);
    gld16(BlorP,            lds + B0n + tid * 16);
    gld16(BlorP + 128 * 64, lds + B0n + 8192 + tid * 16);
  }
  BARRIER(); LGKM0();
  __builtin_amdgcn_s_setprio(1);
  #pragma unroll
  for (int mi = 0; mi < 4; ++mi)
    #pragma unroll
    for (int ni = 0; ni < 4; ++ni) {
      acc[mi][ni] = __builtin_amdgcn_mfma_i32_16x16x64_i8(a[mi], b[ni], acc[mi][ni], 0, 0, 0);
      acc[mi][ni] = __builtin_amdgcn_mfma_i32_16x16x64_i8(a[4 + mi], b[4 + ni], acc[mi][ni], 0, 0, 0);
    }
  __builtin_amdgcn_s_setprio(0);
  BARRIER();

  // ---- phase B
  #pragma unroll
  for (int mi = 0; mi < 4; ++mi) {
    a[mi]     = *(const i32x4*)(lds + A0 + (arow + 64 + mi * 16) * 64 + fsb);
    a[4 + mi] = *(const i32x4*)(lds + A1 + (arow + 64 + mi * 16) * 64 + fsb);
  }
  BARRIER(); LGKM0();
  __builtin_amdgcn_s_setprio(1);
  #pragma unroll
  for (int mi = 0; mi < 4; ++mi)
    #pragma unroll
    for (int ni = 0; ni < 4; ++ni) {
      acc[4 + mi][ni] = __builtin_amdgcn_mfma_i32_16x16x64_i8(a[mi], b[ni], acc[4 + mi][ni], 0, 0, 0);
      acc[4 + mi][ni] = __builtin_amdgcn_mfma_i32_16x16x64_i8(a[4 + mi], b[4 + ni], acc[4 + mi][ni], 0, 0, 0);
    }
  __builtin_amdgcn_s_setprio(0);
  vmw<0>();
  BARRIER();
}

__global__ __launch_bounds__(512, 2) void k_gemmi8(
    const signed char* __restrict__ Aq, const signed char* __restrict__ Bq,
    const float* __restrict__ Sa_r, const float* __restrict__ Sb_r,
    const unsigned short* __restrict__ Alor, const unsigned short* __restrict__ Blor,
    const float* __restrict__ bias,
    const float* __restrict__ nqw, const float* __restrict__ nkw,
    const float* __restrict__ fcos, const float* __restrict__ fsin,
    float* __restrict__ outp) {
  __shared__ char lds[131072];  // 8 regions x 16 KB
  const int tid = threadIdx.x;
  const int w = tid >> 6, l = tid & 63;
  const int wr = w >> 2, wc = w & 3;               // 2M x 4N waves, 128x64 each
  const int l16 = l & 15, g16 = l >> 4;
  // 2D-chunked XCD swizzle (r5): xcd owns by-band [4*xcd,4*xcd+4)
  const int xcd = blockIdx.x & 7;
  const int jj = blockIdx.x >> 3;      // 0..143
  const int chunk = jj / 36;           // 0..3
  const int tt = jj - chunk * 36;      // 0..35
  const int by = xcd * 4 + tt / 9;
  const int bx = chunk * 9 + tt % 9;
  const int n0 = bx * 256, m0 = by * 256;
  const int arow = wr * 128 + l16;
  const int brow = wc * 64 + l16;
  const int fsb = (g16 ^ ((l16 >> 1) & 3)) << 4;       // frag chunk swizzle
  const int sr = tid >> 2;                             // staging row 0..127
  const int ss = (((tid & 3) ^ ((sr >> 1) & 3)) << 4); // pre-swizzled source chunk
  const signed char* Asrc = Aq + (size_t)(m0 + sr) * CDIM + ss;
  const signed char* Bsrc = Bq + (size_t)(n0 + sr) * CDIM + ss;
  const char* AlorP = (const char*)Alor + (size_t)(m0 + sr) * 64 + ss;
  const char* BlorP = (const char*)Blor + (size_t)(n0 + sr) * 64 + ss;
  i32x4 acc[8][4] = {};

  // prologue: stage window 0 (A0[0],A1[0],B0[0],B1[0]); drain; go
  gld16(Asrc,                           lds + tid * 16);
  gld16(Asrc + (size_t)128 * CDIM,      lds + 8192 + tid * 16);
  gld16(Asrc + 64,                      lds + 32768 + tid * 16);
  gld16(Asrc + (size_t)128 * CDIM + 64, lds + 40960 + tid * 16);
  gld16(Bsrc,                           lds + 65536 + tid * 16);
  gld16(Bsrc + (size_t)128 * CDIM,      lds + 73728 + tid * 16);
  gld16(Bsrc + 64,                      lds + 98304 + tid * 16);
  gld16(Bsrc + (size_t)128 * CDIM + 64, lds + 106496 + tid * 16);
  vmw<0>(); BARRIER();

  #pragma unroll 1
  for (int t = 0; t < NW - 1; ++t)
    gemm_window2(lds, acc, Asrc, Bsrc, AlorP, BlorP, tid, arow, brow, fsb, t & 1, t, 0);
  gemm_window2(lds, acc, Asrc, Bsrc, AlorP, BlorP, tid, arow, brow, fsb, (NW - 1) & 1, NW - 1, 1);

  // ---- convert acc -> f32 with row/col scales
  f32x4 facc[8][4];
  float sbv[4];
  #pragma unroll
  for (int ni = 0; ni < 4; ++ni) sbv[ni] = Sb_r[n0 + wc * 64 + ni * 16 + l16];
  #pragma unroll
  for (int q = 0; q < 8; ++q) {
    const f32x4 sa4 = *(const f32x4*)&Sa_r[m0 + wr * 128 + q * 16 + g16 * 4];
    #pragma unroll
    for (int ni = 0; ni < 4; ++ni)
      facc[q][ni] = __builtin_convertvector(acc[q][ni], f32x4) * (sa4 * sbv[ni]);
  }

  // ---- lora bf16 pass (K=32); lora staged into A0[0]=lds+0, B0[0]=lds+65536
  // (NW-1 is odd -> par^1 = 0), published by the last window's end barrier.
  {
    bf16x8 bl[4];
    #pragma unroll
    for (int ni = 0; ni < 4; ++ni)
      bl[ni] = *(const bf16x8*)(lds + 65536 + (brow + ni * 16) * 64 + fsb);
    #pragma unroll
    for (int q = 0; q < 8; ++q) {
      const bf16x8 al = *(const bf16x8*)(lds + (arow + q * 16) * 64 + fsb);
      #pragma unroll
      for (int ni = 0; ni < 4; ++ni)
        facc[q][ni] = __builtin_amdgcn_mfma_f32_16x16x32_bf16(al, bl[ni], facc[q][ni], 0, 0, 0);
    }
  }

  // ---------------- fused epilogue (bias -> RMSNorm+RoPE for q/k)
  float bvv[4];
  #pragma unroll
  for (int ni = 0; ni < 4; ++ni) bvv[ni] = bias[n0 + wc * 64 + ni * 16 + l16];
  #pragma unroll
  for (int q = 0; q < 8; ++q)
    #pragma unroll
    for (int ni = 0; ni < 4; ++ni)
      #pragma unroll
      for (int j = 0; j < 4; ++j) facc[q][ni][j] += bvv[ni];

  if (n0 < 6144) {
    const float* nwt = (n0 < 3072) ? nqw : nkw;
    float nw[4];
    #pragma unroll
    for (int ni = 0; ni < 4; ++ni) nw[ni] = nwt[(wc & 1) * 64 + ni * 16 + l16];

    float part[8][4];
    #pragma unroll
    for (int q = 0; q < 8; ++q)
      #pragma unroll
      for (int j = 0; j < 4; ++j) {
        float ssum = 0.f;
        #pragma unroll
        for (int ni = 0; ni < 4; ++ni) ssum += facc[q][ni][j] * facc[q][ni][j];
        #pragma unroll
        for (int off = 1; off < 16; off <<= 1) ssum += __shfl_xor(ssum, off);
        part[q][j] = ssum;   // per-row partial over this wave's 64 cols
      }

    __syncthreads();                    // LDS regions done; reuse as sq
    float* sq = (float*)lds;            // [2][128][2][2]
    if (l16 == 0) {
      #pragma unroll
      for (int q = 0; q < 8; ++q)
        #pragma unroll
        for (int j = 0; j < 4; ++j) {
          const int r128 = q * 16 + g16 * 4 + j;
          sq[(((wr * 128 + r128) * 2 + (wc >> 1)) * 2) + (wc & 1)] = part[q][j];
        }
    }
    __syncthreads();

    #pragma unroll
    for (int q = 0; q < 8; ++q) {
      #pragma unroll
      for (int j = 0; j < 4; ++j) {
        const int r128 = q * 16 + g16 * 4 + j;
        const float other = sq[(((wr * 128 + r128) * 2 + (wc >> 1)) * 2) + ((wc & 1) ^ 1)];
        const float rinv = 1.0f / sqrtf((part[q][j] + other) * (1.0f / 128.0f) + 1e-6f);
        const int row = m0 + wr * 128 + r128;
        const int sidx = row & 4095;
        #pragma unroll
        for (int ni = 0; ni < 4; ++ni) {
          const int p = (wc & 1) * 32 + ni * 8 + (l16 >> 1);
          const float cv = fcos[(size_t)sidx * 64 + p];
          const float sv = fsin[(size_t)sidx * 64 + p];
          const float v = facc[q][ni][j] * rinv * nw[ni];
          const float o = __shfl_xor(v, 1);
          const float res = ((l & 1) == 0) ? (v * cv - o * sv) : (o * sv + v * cv);
          __builtin_nontemporal_store(res, &outp[(size_t)row * NOUT + n0 + wc * 64 + ni * 16 + l16]);
        }
      }
    }
  } else {
    #pragma unroll
    for (int ni = 0; ni < 4; ++ni) {
      const int gn = n0 + wc * 64 + ni * 16 + l16;
      #pragma unroll
      for (int q = 0; q < 8; ++q) {
        const int gm = m0 + wr * 128 + q * 16 + g16 * 4;
        #pragma unroll
        for (int j = 0; j < 4; ++j)
          __builtin_nontemporal_store(facc[q][ni][j], &outp[(size_t)(gm + j) * NOUT + gn]);
      }
    }
  }
}

extern "C" void kernel_launch(void* const* d_in, const int* in_sizes, int n_in,
                              void* d_out, int out_size, void* d_ws, size_t ws_size,
                              hipStream_t stream) {
  const float* x      = (const float*)d_in[0];
  const float* smooth = (const float*)d_in[1];
  const float* weight = (const float*)d_in[2];
  const float* pd     = (const float*)d_in[3];
  const float* pu     = (const float*)d_in[4];
  const float* bias   = (const float*)d_in[5];
  const float* nqw    = (const float*)d_in[6];
  const float* nkw    = (const float*)d_in[7];
  const float* fcos   = (const float*)d_in[8];
  const float* fsin   = (const float*)d_in[9];
  float* out = (float*)d_out;

  char* ws = (char*)d_ws;
  signed char* Aq   = (signed char*)ws;                       // 25,165,824
  signed char* Bq   = (signed char*)(ws + 25165824);          // 28,311,552
  float* Sa_r       = (float*)(ws + 53477376);                //    32,768
  float* Sb_r       = (float*)(ws + 53510144);                //    36,864
  unsigned short* Alor = (unsigned short*)(ws + 53547008);    //   524,288
  unsigned short* Blor = (unsigned short*)(ws + 54071296);    //   589,824

  k_prep<<<dim3(NOUT + MROWS / 4), dim3(256), 0, stream>>>(
      weight, pu, x, smooth, pd, Bq, Sb_r, Blor, Aq, Sa_r, Alor);
  k_gemmi8<<<dim3(1152), dim3(512), 0, stream>>>(Aq, Bq, Sa_r, Sb_r, Alor, Blor,
                                                 bias, nqw, nkw, fcos, fsin, out);
}